// Round 16
// baseline (246.416 us; speedup 1.0000x reference)
//
#include <hip/hip_runtime.h>
#include <stdint.h>

typedef __attribute__((ext_vector_type(4))) float f32x4;
typedef __attribute__((ext_vector_type(16))) float f32x16;
typedef __attribute__((ext_vector_type(8))) short bf16x8;

#define DEV static __device__ __forceinline__

#define GLOAD16(g, l) __builtin_amdgcn_global_load_lds( \
    (const __attribute__((address_space(1))) void*)(g), \
    (__attribute__((address_space(3))) void*)(l), 16, 0, 0)

DEV unsigned short f2bf(float f){
  union { float f; uint32_t u; } v; v.f = f;
  return (unsigned short)((v.u + 0x7fffu + ((v.u >> 16) & 1u)) >> 16);
}

DEV uint32_t cvtpk(float a, float b){
  uint32_t r; asm("v_cvt_pk_bf16_f32 %0, %1, %2" : "=v"(r) : "v"(a), "v"(b)); return r;
}

DEV f32x4 mfma_bf16(bf16x8 a, bf16x8 b, f32x4 c){
  return __builtin_amdgcn_mfma_f32_16x16x32_bf16(a, b, c, 0, 0, 0);
}

DEV f32x16 mfma32(bf16x8 a, bf16x8 b, f32x16 c){
  return __builtin_amdgcn_mfma_f32_32x32x16_bf16(a, b, c, 0, 0, 0);
}

// ---------------- K0: fm transpose+cvt (z<16) and W cvt (z==16) ----------------
__global__ __launch_bounds__(256) void k_prep(const float* __restrict__ fm,
                                              unsigned short* __restrict__ xt,
                                              const float* __restrict__ wqk,
                                              const float* __restrict__ wv,
                                              unsigned short* __restrict__ wb){
  int z = blockIdx.z;
  int t = threadIdx.x;
  if (z == 16){
    // W concat(w_qk,w_v) f32 -> bf16 [1536][512], 128 blocks x 6 sweeps
    int fid = blockIdx.y * 16 + blockIdx.x;
    #pragma unroll
    for (int s = 0; s < 6; s++){
      int e = (fid * 256 + t) * 4 + s * 131072;
      const float* src = (e < 1024 * 512) ? (wqk + e) : (wv + (e - 1024 * 512));
      f32x4 v = *(const f32x4*)src;
      unsigned short* d = wb + e;
      d[0] = f2bf(v[0]); d[1] = f2bf(v[1]); d[2] = f2bf(v[2]); d[3] = f2bf(v[3]);
    }
    return;
  }
  __shared__ float tile[64][65];
  int b = z, c0 = blockIdx.y * 64, l0 = blockIdx.x * 64;
  int lr = t >> 4;
  int lc4 = (t & 15) * 4;
  const float* src = fm + ((size_t)b * 512 + c0) * 1024 + l0;
  #pragma unroll
  for (int i = 0; i < 4; i++){
    int r = lr + i * 16;
    f32x4 v = *(const f32x4*)&src[(size_t)r * 1024 + lc4];
    tile[r][lc4] = v[0]; tile[r][lc4 + 1] = v[1];
    tile[r][lc4 + 2] = v[2]; tile[r][lc4 + 3] = v[3];
  }
  __syncthreads();
  int j = t & 7;
  int lrow = t >> 3;
  unsigned short* dst = xt + ((size_t)b * 1024 + l0) * 512 + c0;
  #pragma unroll
  for (int i = 0; i < 2; i++){
    int l = lrow + i * 32;
    unsigned short tmp[8];
    #pragma unroll
    for (int u = 0; u < 8; u++) tmp[u] = f2bf(tile[j * 8 + u][l]);
    *(uint4*)&dst[(size_t)l * 512 + j * 8] = *(const uint4*)tmp;
  }
}

// ---------------- K1: merged projection GEMMs ----------------
// y<8:  MODE0  C = XT_b[1024][512] x Wqk[1024][512]^T -> q(scaled)/k [bh][l][d]
// y>=8: MODE1  C = Wv[512][512]    x XT_b[1024][512]^T -> v [bh][dv][l]
__global__ __launch_bounds__(256, 3) void k_projall(const unsigned short* __restrict__ xt,
                                                    const unsigned short* __restrict__ wb,
                                                    unsigned short* __restrict__ qbuf,
                                                    unsigned short* __restrict__ kbuf,
                                                    unsigned short* __restrict__ vbuf){
  __shared__ unsigned short Al[128][64];
  __shared__ unsigned short Bl[128][64];
  int b = blockIdx.z;
  int y = blockIdx.y;
  bool mode1 = (y >= 8);
  const unsigned short* A;
  const unsigned short* B;
  int m0, n0;
  if (!mode1){
    A = xt + (size_t)b * 1024 * 512;
    B = wb;
    m0 = blockIdx.x * 128;
    n0 = y * 128;
  } else {
    A = wb + (size_t)1024 * 512;
    B = xt + (size_t)b * 1024 * 512;
    m0 = (y - 8) * 128;
    n0 = blockIdx.x * 128;
  }
  int t = threadIdx.x;
  int lane = t & 63, w = t >> 6;
  int wm = (w >> 1) * 64, wn = (w & 1) * 64;
  int l15 = lane & 15, lg = lane >> 4;
  int srow = lane >> 3;
  int scol = (lane & 7) * 8;
  f32x4 acc[4][4];
  for (int m = 0; m < 4; m++) for (int n = 0; n < 4; n++) acc[m][n] = (f32x4)(0.f);
  for (int k0 = 0; k0 < 512; k0 += 64){
    __syncthreads();
    #pragma unroll
    for (int i = 0; i < 4; i++){
      int j = w * 4 + i;
      GLOAD16(&A[(size_t)(m0 + j * 8 + srow) * 512 + k0 + scol], &Al[j * 8][0]);
      GLOAD16(&B[(size_t)(n0 + j * 8 + srow) * 512 + k0 + scol], &Bl[j * 8][0]);
    }
    __syncthreads();
    for (int dc = 0; dc < 2; dc++){
      bf16x8 af[4], bfr[4];
      for (int m = 0; m < 4; m++) af[m]  = *(const bf16x8*)&Al[wm + m * 16 + l15][dc * 32 + lg * 8];
      for (int n = 0; n < 4; n++) bfr[n] = *(const bf16x8*)&Bl[wn + n * 16 + l15][dc * 32 + lg * 8];
      for (int m = 0; m < 4; m++)
        for (int n = 0; n < 4; n++)
          acc[m][n] = mfma_bf16(af[m], bfr[n], acc[m][n]);
    }
  }
  for (int m = 0; m < 4; m++) for (int n = 0; n < 4; n++) for (int r = 0; r < 4; r++){
    int row = m0 + wm + m * 16 + lg * 4 + r;
    int col = n0 + wn + n * 16 + l15;
    float val = acc[m][n][r];
    if (!mode1){
      if (col < 512){
        int h = col >> 7, d = col & 127;
        qbuf[(((size_t)b * 4 + h) * 1024 + row) * 128 + d] = f2bf(val * 0.08838834764831845f);
      } else {
        int c2 = col - 512;
        int h = c2 >> 7, d = c2 & 127;
        kbuf[(((size_t)b * 4 + h) * 1024 + row) * 128 + d] = f2bf(val);
      }
    } else {
      vbuf[(((size_t)b * 4 + (row >> 7)) * 128 + (row & 127)) * 1024 + col] = f2bf(val);
    }
  }
}

// ---------------- K2: rel logits  Rel[bh][p][0:32]=rh(y), [32:64]=rw(j) ----------------
__global__ __launch_bounds__(256, 2) void k_rel(const unsigned short* __restrict__ qbuf,
                                                const float* __restrict__ relh,
                                                const float* __restrict__ relw,
                                                float* __restrict__ Rel){
  int t = threadIdx.x;
  int lane = t & 63;
  int xi = blockIdx.x * 4 + (t >> 6);
  int bh = blockIdx.y;
  int mode = blockIdx.z;
  int l15 = lane & 15, lg = lane >> 4;
  const float* rel = (mode == 0) ? relh : relw;
  f32x4 acc[2][2];
  for (int m = 0; m < 2; m++) for (int n = 0; n < 2; n++) acc[m][n] = (f32x4)(0.f);
  for (int dc = 0; dc < 4; dc++){
    bf16x8 af[2], bb[2];
    for (int m = 0; m < 2; m++){
      int p = (mode == 0) ? (xi * 32 + m * 16 + l15) : ((m * 16 + l15) * 32 + xi);
      af[m] = *(const bf16x8*)&qbuf[((size_t)bh * 1024 + p) * 128 + dc * 32 + lg * 8];
    }
    for (int n = 0; n < 2; n++){
      int mrow = n * 16 + l15 - xi + 31;
      const float* rp = &rel[(size_t)mrow * 128 + dc * 32 + lg * 8];
      f32x4 r0 = *(const f32x4*)rp;
      f32x4 r1 = *(const f32x4*)(rp + 4);
      bf16x8 tt;
      for (int e = 0; e < 4; e++){ tt[e] = (short)f2bf(r0[e]); tt[e + 4] = (short)f2bf(r1[e]); }
      bb[n] = tt;
    }
    for (int m = 0; m < 2; m++)
      for (int n = 0; n < 2; n++)
        acc[m][n] = mfma_bf16(af[m], bb[n], acc[m][n]);
  }
  for (int m = 0; m < 2; m++) for (int n = 0; n < 2; n++) for (int r = 0; r < 4; r++){
    int a = m * 16 + lg * 4 + r;
    int outc = n * 16 + l15;
    int p = (mode == 0) ? (xi * 32 + a) : (a * 32 + xi);
    Rel[((size_t)bh * 1024 + p) * 64 + ((mode == 0) ? outc : 32 + outc)] = acc[m][n][r];
  }
}

// ---------------- K3: fused flash attention (R15 verbatim) ----------------
__global__ __launch_bounds__(256, 2) void k_attn(const unsigned short* __restrict__ qbuf,
                                                 const unsigned short* __restrict__ kbuf,
                                                 const unsigned short* __restrict__ vbuf,
                                                 const float* __restrict__ Rel,
                                                 float* __restrict__ out){
  __shared__ unsigned short Kl[64 * 128];   // [key][d], 4-bit XOR-swizzled cols
  __shared__ unsigned short Vl[128 * 64];   // [dv][key], 3-bit XOR-swizzled cols
  int bh = blockIdx.x;
  int q0 = blockIdx.y * 128;
  int t = threadIdx.x;
  int lane = t & 63, w = t >> 6;
  int l31 = lane & 31, hi = lane >> 5;
  int swzK = (l31 & 15) * 8;
  int swzV = (l31 & 7) * 8;
  int q = q0 + w * 32 + l31;
  const unsigned short* qg = qbuf + (size_t)bh * 1024 * 128;
  const unsigned short* kg = kbuf + (size_t)bh * 1024 * 128;
  const unsigned short* vg = vbuf + (size_t)bh * 128 * 1024;
  const float* relbh = Rel + (size_t)bh * 1024 * 64;

  bf16x8 qf[8];
  #pragma unroll
  for (int ks = 0; ks < 8; ks++)
    qf[ks] = *(const bf16x8*)&qg[(size_t)q * 128 + ks * 16 + hi * 8];

  float rwv[16];
  #pragma unroll
  for (int r = 0; r < 16; r++)
    rwv[r] = relbh[(size_t)q * 64 + 32 + (r & 3) + 8 * (r >> 2) + 4 * hi];

  bf16x8 ones;
  #pragma unroll
  for (int e = 0; e < 8; e++) ones[e] = (short)0x3F80;  // bf16 1.0

  f32x16 o[4], osum;
  #pragma unroll
  for (int vb = 0; vb < 4; vb++) o[vb] = (f32x16)(0.f);
  osum = (f32x16)(0.f);

  bf16x8 kpre[4], vpre[4];
  #pragma unroll
  for (int i = 0; i < 4; i++){
    int c = t + i * 256;
    kpre[i] = *(const bf16x8*)&kg[(size_t)(c >> 4) * 128 + (c & 15) * 8];
    vpre[i] = *(const bf16x8*)&vg[(size_t)(c >> 3) * 1024 + (c & 7) * 8];
  }

  for (int kv0 = 0; kv0 < 1024; kv0 += 64){
    __syncthreads();
    #pragma unroll
    for (int i = 0; i < 4; i++){
      int c = t + i * 256;
      int kr = c >> 4;
      int vr = c >> 3;
      *(bf16x8*)&Kl[kr * 128 + (((c & 15) * 8) ^ ((kr & 15) * 8))] = kpre[i];
      *(bf16x8*)&Vl[vr * 64 + (((c & 7) * 8) ^ ((vr & 7) * 8))] = vpre[i];
    }
    __syncthreads();
    if (kv0 + 64 < 1024){
      int kvn = kv0 + 64;
      #pragma unroll
      for (int i = 0; i < 4; i++){
        int c = t + i * 256;
        kpre[i] = *(const bf16x8*)&kg[(size_t)(kvn + (c >> 4)) * 128 + (c & 15) * 8];
        vpre[i] = *(const bf16x8*)&vg[(size_t)(c >> 3) * 1024 + kvn + (c & 7) * 8];
      }
    }

    // QK: S^T[key][q] for two 32-key blocks; A=K from Kl, B=Q regs
    f32x16 s0 = (f32x16)(0.f), s1 = (f32x16)(0.f);
    __builtin_amdgcn_s_setprio(1);
    #pragma unroll
    for (int ks = 0; ks < 8; ks++){
      bf16x8 kf0 = *(const bf16x8*)&Kl[(size_t)l31 * 128 + ((ks * 16 + hi * 8) ^ swzK)];
      bf16x8 kf1 = *(const bf16x8*)&Kl[(size_t)(32 + l31) * 128 + ((ks * 16 + hi * 8) ^ swzK)];
      s0 = mfma32(kf0, qf[ks], s0);
      s1 = mfma32(kf1, qf[ks], s1);
    }
    __builtin_amdgcn_s_setprio(0);

    float rh0 = relbh[(size_t)q * 64 + (kv0 >> 5)];
    float rh1 = relbh[(size_t)q * 64 + (kv0 >> 5) + 1];

    float pb0[16], pb1[16];
    #pragma unroll
    for (int r = 0; r < 16; r++){
      pb0[r] = __expf(fminf(s0[r] + rh0 + rwv[r], 60.f));
      pb1[r] = __expf(fminf(s1[r] + rh1 + rwv[r], 60.f));
    }

    __builtin_amdgcn_s_setprio(1);
    #pragma unroll
    for (int kk = 0; kk < 4; kk++){
      const float* pb = (kk < 2) ? pb0 : pb1;
      int kkk = kk & 1;
      uint32_t c0 = cvtpk(pb[kkk * 8 + 0], pb[kkk * 8 + 1]);
      uint32_t c1 = cvtpk(pb[kkk * 8 + 2], pb[kkk * 8 + 3]);
      uint32_t c2 = cvtpk(pb[kkk * 8 + 4], pb[kkk * 8 + 5]);
      uint32_t c3 = cvtpk(pb[kkk * 8 + 6], pb[kkk * 8 + 7]);
      asm("v_permlane32_swap_b32 %0, %1" : "+v"(c0), "+v"(c2));
      asm("v_permlane32_swap_b32 %0, %1" : "+v"(c1), "+v"(c3));
      uint32_t words[4] = {c0, c1, c2, c3};
      bf16x8 pfrag = *(const bf16x8*)words;
      int vcol = kk * 16 + hi * 8;
      #pragma unroll
      for (int vb = 0; vb < 4; vb++){
        bf16x8 vf = *(const bf16x8*)&Vl[(size_t)(vb * 32 + l31) * 64 + (vcol ^ swzV)];
        o[vb] = mfma32(vf, pfrag, o[vb]);
      }
      osum = mfma32(ones, pfrag, osum);
    }
    __builtin_amdgcn_s_setprio(0);
  }

  float inv = 1.f / osum[0];
  float* outb = out + (size_t)bh * 128 * 1024;
  #pragma unroll
  for (int vb = 0; vb < 4; vb++)
    #pragma unroll
    for (int r = 0; r < 16; r++){
      int dv = vb * 32 + (r & 3) + 8 * (r >> 2) + 4 * hi;
      outb[(size_t)dv * 1024 + q] = o[vb][r] * inv;
    }
}

extern "C" void kernel_launch(void* const* d_in, const int* in_sizes, int n_in,
                              void* d_out, int out_size, void* d_ws, size_t ws_size,
                              hipStream_t stream){
  const float* fm   = (const float*)d_in[0];
  const float* wqk  = (const float*)d_in[1];
  const float* wv   = (const float*)d_in[2];
  const float* relh = (const float*)d_in[3];
  const float* relw = (const float*)d_in[4];
  float* out = (float*)d_out;
  char* ws = (char*)d_ws;
  if (ws_size < (size_t)68681728) return;

  unsigned short* qb = (unsigned short*)(ws);
  unsigned short* kb = (unsigned short*)(ws + ((size_t)16 << 20));
  unsigned short* vb = (unsigned short*)(ws + ((size_t)32 << 20));
  unsigned short* xt = (unsigned short*)(ws + ((size_t)48 << 20));
  float* Rel         = (float*)(ws + ((size_t)48 << 20));
  unsigned short* wb = (unsigned short*)(ws + ((size_t)64 << 20));

  hipLaunchKernelGGL(k_prep, dim3(16, 8, 17), dim3(256), 0, stream, fm, xt, wqk, wv, wb);
  hipLaunchKernelGGL(k_projall, dim3(8, 12, 16), dim3(256), 0, stream, xt, wb, qb, kb, vb);
  hipLaunchKernelGGL(k_rel, dim3(8, 64, 2), dim3(256), 0, stream, qb, relh, relw, Rel);
  hipLaunchKernelGGL(k_attn, dim3(64, 8), dim3(256), 0, stream, qb, kb, vb, Rel, out);
}

// Round 17
// 117.712 us; speedup vs baseline: 2.0934x; 2.0934x over previous
//
#include <hip/hip_runtime.h>
#include <stdint.h>

typedef __attribute__((ext_vector_type(4))) float f32x4;
typedef __attribute__((ext_vector_type(16))) float f32x16;
typedef __attribute__((ext_vector_type(8))) short bf16x8;

#define DEV static __device__ __forceinline__

#define GLOAD16(g, l) __builtin_amdgcn_global_load_lds( \
    (const __attribute__((address_space(1))) void*)(g), \
    (__attribute__((address_space(3))) void*)(l), 16, 0, 0)

DEV unsigned short f2bf(float f){
  union { float f; uint32_t u; } v; v.f = f;
  return (unsigned short)((v.u + 0x7fffu + ((v.u >> 16) & 1u)) >> 16);
}

DEV uint32_t cvtpk(float a, float b){
  uint32_t r; asm("v_cvt_pk_bf16_f32 %0, %1, %2" : "=v"(r) : "v"(a), "v"(b)); return r;
}

DEV f32x4 mfma_bf16(bf16x8 a, bf16x8 b, f32x4 c){
  return __builtin_amdgcn_mfma_f32_16x16x32_bf16(a, b, c, 0, 0, 0);
}

DEV f32x16 mfma32(bf16x8 a, bf16x8 b, f32x16 c){
  return __builtin_amdgcn_mfma_f32_32x32x16_bf16(a, b, c, 0, 0, 0);
}

// ---------------- K0: fm transpose+cvt (z<16) and W cvt (z==16) ----------------
__global__ __launch_bounds__(256) void k_prep(const float* __restrict__ fm,
                                              unsigned short* __restrict__ xt,
                                              const float* __restrict__ wqk,
                                              const float* __restrict__ wv,
                                              unsigned short* __restrict__ wb){
  int z = blockIdx.z;
  int t = threadIdx.x;
  if (z == 16){
    int fid = blockIdx.y * 16 + blockIdx.x;   // 0..127
    #pragma unroll
    for (int s = 0; s < 6; s++){
      int e = (fid * 256 + t) * 4 + s * 131072;
      const float* src = (e < 1024 * 512) ? (wqk + e) : (wv + (e - 1024 * 512));
      f32x4 v = *(const f32x4*)src;
      unsigned short* d = wb + e;
      d[0] = f2bf(v[0]); d[1] = f2bf(v[1]); d[2] = f2bf(v[2]); d[3] = f2bf(v[3]);
    }
    return;
  }
  __shared__ float tile[64][65];
  int b = z, c0 = blockIdx.y * 64, l0 = blockIdx.x * 64;
  int lr = t >> 4;
  int lc4 = (t & 15) * 4;
  const float* src = fm + ((size_t)b * 512 + c0) * 1024 + l0;
  #pragma unroll
  for (int i = 0; i < 4; i++){
    int r = lr + i * 16;
    f32x4 v = *(const f32x4*)&src[(size_t)r * 1024 + lc4];
    tile[r][lc4] = v[0]; tile[r][lc4 + 1] = v[1];
    tile[r][lc4 + 2] = v[2]; tile[r][lc4 + 3] = v[3];
  }
  __syncthreads();
  int j = t & 7;
  int lrow = t >> 3;
  unsigned short* dst = xt + ((size_t)b * 1024 + l0) * 512 + c0;
  #pragma unroll
  for (int i = 0; i < 2; i++){
    int l = lrow + i * 32;
    unsigned short tmp[8];
    #pragma unroll
    for (int u = 0; u < 8; u++) tmp[u] = f2bf(tile[j * 8 + u][l]);
    *(uint4*)&dst[(size_t)l * 512 + j * 8] = *(const uint4*)tmp;
  }
}

// ---------------- K1: gemm_bt  C = A(MxK) * B(NxK)^T, bf16, K=512 (R15-proven) ----------------
template<int MODE>
__global__ __launch_bounds__(256, 3) void k_proj(const unsigned short* __restrict__ Abase,
                                                 const unsigned short* __restrict__ Bbase,
                                                 unsigned short* __restrict__ qbuf,
                                                 unsigned short* __restrict__ kbuf,
                                                 unsigned short* __restrict__ vbuf){
  __shared__ unsigned short Al[128][64];
  __shared__ unsigned short Bl[128][64];
  int b = blockIdx.z;
  const unsigned short* A = Abase + (MODE == 0 ? (size_t)b * 1024 * 512 : 0);
  const unsigned short* B = Bbase + (MODE == 0 ? 0 : (size_t)b * 1024 * 512);
  int m0 = blockIdx.x * 128, n0 = blockIdx.y * 128;
  int t = threadIdx.x;
  int lane = t & 63, w = t >> 6;
  int wm = (w >> 1) * 64, wn = (w & 1) * 64;
  int l15 = lane & 15, lg = lane >> 4;
  int srow = lane >> 3;
  int scol = (lane & 7) * 8;
  f32x4 acc[4][4];
  for (int m = 0; m < 4; m++) for (int n = 0; n < 4; n++) acc[m][n] = (f32x4)(0.f);
  for (int k0 = 0; k0 < 512; k0 += 64){
    __syncthreads();
    #pragma unroll
    for (int i = 0; i < 4; i++){
      int j = w * 4 + i;
      GLOAD16(&A[(size_t)(m0 + j * 8 + srow) * 512 + k0 + scol], &Al[j * 8][0]);
      GLOAD16(&B[(size_t)(n0 + j * 8 + srow) * 512 + k0 + scol], &Bl[j * 8][0]);
    }
    __syncthreads();
    for (int dc = 0; dc < 2; dc++){
      bf16x8 af[4], bfr[4];
      for (int m = 0; m < 4; m++) af[m]  = *(const bf16x8*)&Al[wm + m * 16 + l15][dc * 32 + lg * 8];
      for (int n = 0; n < 4; n++) bfr[n] = *(const bf16x8*)&Bl[wn + n * 16 + l15][dc * 32 + lg * 8];
      for (int m = 0; m < 4; m++)
        for (int n = 0; n < 4; n++)
          acc[m][n] = mfma_bf16(af[m], bfr[n], acc[m][n]);
    }
  }
  for (int m = 0; m < 4; m++) for (int n = 0; n < 4; n++) for (int r = 0; r < 4; r++){
    int row = m0 + wm + m * 16 + lg * 4 + r;
    int col = n0 + wn + n * 16 + l15;
    float val = acc[m][n][r];
    if (MODE == 0){
      if (col < 512){
        int h = col >> 7, d = col & 127;
        qbuf[(((size_t)b * 4 + h) * 1024 + row) * 128 + d] = f2bf(val * 0.08838834764831845f);
      } else {
        int c2 = col - 512;
        int h = c2 >> 7, d = c2 & 127;
        kbuf[(((size_t)b * 4 + h) * 1024 + row) * 128 + d] = f2bf(val);
      }
    } else {
      vbuf[(((size_t)b * 4 + (row >> 7)) * 128 + (row & 127)) * 1024 + col] = f2bf(val);
    }
  }
}

// ---------------- K2: rel logits  Rel[bh][p][0:32]=rh(y), [32:64]=rw(j) ----------------
__global__ __launch_bounds__(256, 2) void k_rel(const unsigned short* __restrict__ qbuf,
                                                const float* __restrict__ relh,
                                                const float* __restrict__ relw,
                                                float* __restrict__ Rel){
  int t = threadIdx.x;
  int lane = t & 63;
  int xi = blockIdx.x * 4 + (t >> 6);
  int bh = blockIdx.y;
  int mode = blockIdx.z;
  int l15 = lane & 15, lg = lane >> 4;
  const float* rel = (mode == 0) ? relh : relw;
  f32x4 acc[2][2];
  for (int m = 0; m < 2; m++) for (int n = 0; n < 2; n++) acc[m][n] = (f32x4)(0.f);
  for (int dc = 0; dc < 4; dc++){
    bf16x8 af[2], bb[2];
    for (int m = 0; m < 2; m++){
      int p = (mode == 0) ? (xi * 32 + m * 16 + l15) : ((m * 16 + l15) * 32 + xi);
      af[m] = *(const bf16x8*)&qbuf[((size_t)bh * 1024 + p) * 128 + dc * 32 + lg * 8];
    }
    for (int n = 0; n < 2; n++){
      int mrow = n * 16 + l15 - xi + 31;
      const float* rp = &rel[(size_t)mrow * 128 + dc * 32 + lg * 8];
      f32x4 r0 = *(const f32x4*)rp;
      f32x4 r1 = *(const f32x4*)(rp + 4);
      bf16x8 tt;
      for (int e = 0; e < 4; e++){ tt[e] = (short)f2bf(r0[e]); tt[e + 4] = (short)f2bf(r1[e]); }
      bb[n] = tt;
    }
    for (int m = 0; m < 2; m++)
      for (int n = 0; n < 2; n++)
        acc[m][n] = mfma_bf16(af[m], bb[n], acc[m][n]);
  }
  for (int m = 0; m < 2; m++) for (int n = 0; n < 2; n++) for (int r = 0; r < 4; r++){
    int a = m * 16 + lg * 4 + r;
    int outc = n * 16 + l15;
    int p = (mode == 0) ? (xi * 32 + a) : (a * 32 + xi);
    Rel[((size_t)bh * 1024 + p) * 64 + ((mode == 0) ? outc : 32 + outc)] = acc[m][n][r];
  }
}

// ---------------- K3: fused flash attention (R15 verbatim) ----------------
__global__ __launch_bounds__(256, 2) void k_attn(const unsigned short* __restrict__ qbuf,
                                                 const unsigned short* __restrict__ kbuf,
                                                 const unsigned short* __restrict__ vbuf,
                                                 const float* __restrict__ Rel,
                                                 float* __restrict__ out){
  __shared__ unsigned short Kl[64 * 128];   // [key][d], 4-bit XOR-swizzled cols
  __shared__ unsigned short Vl[128 * 64];   // [dv][key], 3-bit XOR-swizzled cols
  int bh = blockIdx.x;
  int q0 = blockIdx.y * 128;
  int t = threadIdx.x;
  int lane = t & 63, w = t >> 6;
  int l31 = lane & 31, hi = lane >> 5;
  int swzK = (l31 & 15) * 8;
  int swzV = (l31 & 7) * 8;
  int q = q0 + w * 32 + l31;
  const unsigned short* qg = qbuf + (size_t)bh * 1024 * 128;
  const unsigned short* kg = kbuf + (size_t)bh * 1024 * 128;
  const unsigned short* vg = vbuf + (size_t)bh * 128 * 1024;
  const float* relbh = Rel + (size_t)bh * 1024 * 64;

  bf16x8 qf[8];
  #pragma unroll
  for (int ks = 0; ks < 8; ks++)
    qf[ks] = *(const bf16x8*)&qg[(size_t)q * 128 + ks * 16 + hi * 8];

  float rwv[16];
  #pragma unroll
  for (int r = 0; r < 16; r++)
    rwv[r] = relbh[(size_t)q * 64 + 32 + (r & 3) + 8 * (r >> 2) + 4 * hi];

  bf16x8 ones;
  #pragma unroll
  for (int e = 0; e < 8; e++) ones[e] = (short)0x3F80;  // bf16 1.0

  f32x16 o[4], osum;
  #pragma unroll
  for (int vb = 0; vb < 4; vb++) o[vb] = (f32x16)(0.f);
  osum = (f32x16)(0.f);

  bf16x8 kpre[4], vpre[4];
  #pragma unroll
  for (int i = 0; i < 4; i++){
    int c = t + i * 256;
    kpre[i] = *(const bf16x8*)&kg[(size_t)(c >> 4) * 128 + (c & 15) * 8];
    vpre[i] = *(const bf16x8*)&vg[(size_t)(c >> 3) * 1024 + (c & 7) * 8];
  }

  for (int kv0 = 0; kv0 < 1024; kv0 += 64){
    __syncthreads();
    #pragma unroll
    for (int i = 0; i < 4; i++){
      int c = t + i * 256;
      int kr = c >> 4;
      int vr = c >> 3;
      *(bf16x8*)&Kl[kr * 128 + (((c & 15) * 8) ^ ((kr & 15) * 8))] = kpre[i];
      *(bf16x8*)&Vl[vr * 64 + (((c & 7) * 8) ^ ((vr & 7) * 8))] = vpre[i];
    }
    __syncthreads();
    if (kv0 + 64 < 1024){
      int kvn = kv0 + 64;
      #pragma unroll
      for (int i = 0; i < 4; i++){
        int c = t + i * 256;
        kpre[i] = *(const bf16x8*)&kg[(size_t)(kvn + (c >> 4)) * 128 + (c & 15) * 8];
        vpre[i] = *(const bf16x8*)&vg[(size_t)(c >> 3) * 1024 + kvn + (c & 7) * 8];
      }
    }

    // QK: S^T[key][q] for two 32-key blocks; A=K from Kl, B=Q regs
    f32x16 s0 = (f32x16)(0.f), s1 = (f32x16)(0.f);
    __builtin_amdgcn_s_setprio(1);
    #pragma unroll
    for (int ks = 0; ks < 8; ks++){
      bf16x8 kf0 = *(const bf16x8*)&Kl[(size_t)l31 * 128 + ((ks * 16 + hi * 8) ^ swzK)];
      bf16x8 kf1 = *(const bf16x8*)&Kl[(size_t)(32 + l31) * 128 + ((ks * 16 + hi * 8) ^ swzK)];
      s0 = mfma32(kf0, qf[ks], s0);
      s1 = mfma32(kf1, qf[ks], s1);
    }
    __builtin_amdgcn_s_setprio(0);

    float rh0 = relbh[(size_t)q * 64 + (kv0 >> 5)];
    float rh1 = relbh[(size_t)q * 64 + (kv0 >> 5) + 1];

    float pb0[16], pb1[16];
    #pragma unroll
    for (int r = 0; r < 16; r++){
      pb0[r] = __expf(fminf(s0[r] + rh0 + rwv[r], 60.f));
      pb1[r] = __expf(fminf(s1[r] + rh1 + rwv[r], 60.f));
    }

    __builtin_amdgcn_s_setprio(1);
    #pragma unroll
    for (int kk = 0; kk < 4; kk++){
      const float* pb = (kk < 2) ? pb0 : pb1;
      int kkk = kk & 1;
      uint32_t c0 = cvtpk(pb[kkk * 8 + 0], pb[kkk * 8 + 1]);
      uint32_t c1 = cvtpk(pb[kkk * 8 + 2], pb[kkk * 8 + 3]);
      uint32_t c2 = cvtpk(pb[kkk * 8 + 4], pb[kkk * 8 + 5]);
      uint32_t c3 = cvtpk(pb[kkk * 8 + 6], pb[kkk * 8 + 7]);
      asm("v_permlane32_swap_b32 %0, %1" : "+v"(c0), "+v"(c2));
      asm("v_permlane32_swap_b32 %0, %1" : "+v"(c1), "+v"(c3));
      uint32_t words[4] = {c0, c1, c2, c3};
      bf16x8 pfrag = *(const bf16x8*)words;
      int vcol = kk * 16 + hi * 8;
      #pragma unroll
      for (int vb = 0; vb < 4; vb++){
        bf16x8 vf = *(const bf16x8*)&Vl[(size_t)(vb * 32 + l31) * 64 + (vcol ^ swzV)];
        o[vb] = mfma32(vf, pfrag, o[vb]);
      }
      osum = mfma32(ones, pfrag, osum);
    }
    __builtin_amdgcn_s_setprio(0);
  }

  float inv = 1.f / osum[0];
  float* outb = out + (size_t)bh * 128 * 1024;
  #pragma unroll
  for (int vb = 0; vb < 4; vb++)
    #pragma unroll
    for (int r = 0; r < 16; r++){
      int dv = vb * 32 + (r & 3) + 8 * (r >> 2) + 4 * hi;
      outb[(size_t)dv * 1024 + q] = o[vb][r] * inv;
    }
}

extern "C" void kernel_launch(void* const* d_in, const int* in_sizes, int n_in,
                              void* d_out, int out_size, void* d_ws, size_t ws_size,
                              hipStream_t stream){
  const float* fm   = (const float*)d_in[0];
  const float* wqk  = (const float*)d_in[1];
  const float* wv   = (const float*)d_in[2];
  const float* relh = (const float*)d_in[3];
  const float* relw = (const float*)d_in[4];
  float* out = (float*)d_out;
  char* ws = (char*)d_ws;
  if (ws_size < (size_t)68681728) return;

  unsigned short* qb = (unsigned short*)(ws);
  unsigned short* kb = (unsigned short*)(ws + ((size_t)16 << 20));
  unsigned short* vb = (unsigned short*)(ws + ((size_t)32 << 20));
  unsigned short* xt = (unsigned short*)(ws + ((size_t)48 << 20));
  float* Rel         = (float*)(ws + ((size_t)48 << 20));
  unsigned short* wb = (unsigned short*)(ws + ((size_t)64 << 20));

  hipLaunchKernelGGL(k_prep, dim3(16, 8, 17), dim3(256), 0, stream, fm, xt, wqk, wv, wb);
  hipLaunchKernelGGL(k_proj<0>, dim3(8, 8, 16), dim3(256), 0, stream, xt, wb, qb, kb, vb);
  hipLaunchKernelGGL(k_proj<1>, dim3(4, 8, 16), dim3(256), 0, stream,
                     wb + (size_t)1024 * 512, xt, qb, kb, vb);
  hipLaunchKernelGGL(k_rel, dim3(8, 64, 2), dim3(256), 0, stream, qb, relh, relw, Rel);
  hipLaunchKernelGGL(k_attn, dim3(64, 8), dim3(256), 0, stream, qb, kb, vb, Rel, out);
}